// Round 13
// baseline (58.659 us; speedup 1.0000x reference)
//
#include <hip/hip_runtime.h>

// Problem constants (match the JAX reference)
constexpr int BATCH      = 256;
constexpr int T          = 100;
constexpr int J          = 32;
constexpr int EDGES      = 101;
constexpr int NBINS      = 100;
constexpr int ROW_FLOATS = T * J * 3;      // 9600 floats per row
constexpr int HALF_T     = 50;             // timesteps per half-row
constexpr int TSTRIDE    = 97;             // float2 units per timestep (96 used + 1 pad)
constexpr int NREP       = 32;             // histogram replicas (rep = lane&31)
constexpr int NTH        = 1024;           // 16 waves/block, 2 blocks/CU -> 8 waves/SIMD
constexpr float EPSF     = 1e-8f;
constexpr float NTOT     = 102400.0f;      // T*J*J = counts.sum()

// ws layout (ALL bytes plain-stored before any read — no zeroing, no atomics):
//   [0, 1KB)       float wmax[BATCH]                  squared row max (both siblings
//                                                     store the identical value)
//   [1KB, +400KB)  uint  whist[BATCH][2half][2ds][100] per-block slices, summed in k_jsd
constexpr size_t WS_HIST_OFF = 1024;

// Raw v_sqrt_f32 (~1 ulp) — guess only; exact binning via squared-domain thresholds.
__device__ __forceinline__ float sqrt_approx(float s) {
    float r;
    asm("v_sqrt_f32 %0, %1" : "=v"(r) : "v"(s));
    return r;
}

// ---- K1: per-row-half pair kernel. Each block: full-row max (stage other half,
// passA; stage own half, passA) then histogram of its OWN half (still resident).
__global__ __launch_bounds__(NTH, 8)   // 8 waves/EU min => VGPR<=64 => 2 blocks/CU
void k_pair(const float* __restrict__ g1all, const float* __restrict__ g2all,
            float* __restrict__ wmax, unsigned int* __restrict__ whist)
{
#pragma clang fp contract(off)
    // Interleaved point layout, float2 units: point (t,c) at t*TSTRIDE + c*3 =
    // {x1y1, x2y2, z1z2} -> 3x ds_read_b64 covers BOTH datasets.
    __shared__ float2 spt[HALF_T * TSTRIDE];         // 38,800 B
    __shared__ unsigned int hist[2][NREP][EDGES];    // 25,856 B
    __shared__ float sqe[EDGES];                     // squared-domain thresholds m_i
    __shared__ float2 SQ2[NBINS];                    // {m_i, m_{i+1}} pairs
    __shared__ float sred[NTH / 64];
    __shared__ float s_mx;

    const int tid  = threadIdx.x, bh = blockIdx.x;
    const int row  = bh >> 1, half = bh & 1;
    const int hw   = tid >> 5;    // half-wave id in [0,32): owns timesteps hw, hw+32
    const int a    = tid & 31;    // own point index within a timestep
    const float* p1 = g1all + (size_t)row * ROW_FLOATS;
    const float* p2 = g2all + (size_t)row * ROW_FLOATS;

    // Stage 50 timesteps (both datasets) starting at timestep tstart.
    auto stage = [&](int tstart) {
        const float* q1 = p1 + tstart * (J * 3);
        const float* q2 = p2 + tstart * (J * 3);
        for (int k = tid; k < HALF_T * J; k += NTH) {
            const int t = k >> 5, c = k & 31, g = 3 * k;
            const int b = t * TSTRIDE + c * 3;
            spt[b + 0] = make_float2(q1[g],     q1[g + 1]);
            spt[b + 1] = make_float2(q2[g],     q2[g + 1]);
            spt[b + 2] = make_float2(q1[g + 2], q2[g + 2]);
        }
    };

    // Rotation enumeration over the staged 50 timesteps: lane a vs (a+k)&31.
    auto passA = [&](float vmax) -> float {
        for (int r = 0; r < 2; ++r) {
            const int t = r * 32 + hw;
            if (t < HALF_T) {                        // wave-uniform (hw pairs per wave)
                const int b = t * TSTRIDE;
                const float2 o0 = spt[b + a * 3];
                const float2 o1 = spt[b + a * 3 + 1];
                const float2 o2 = spt[b + a * 3 + 2];
#pragma unroll 4
                for (int k = 1; k <= 16; ++k) {
                    const int c = b + ((a + k) & 31) * 3;
                    const float2 c0 = spt[c], c1 = spt[c + 1], c2 = spt[c + 2];
                    float dx1 = o0.x - c0.x, dy1 = o0.y - c0.y, dz1 = o2.x - c2.x;
                    float s1 = dx1 * dx1 + dy1 * dy1 + dz1 * dz1;  // no FMA
                    float dx2 = o1.x - c1.x, dy2 = o1.y - c1.y, dz2 = o2.y - c2.y;
                    float s2 = dx2 * dx2 + dy2 * dy2 + dz2 * dz2;
                    vmax = fmaxf(vmax, fmaxf(s1, s2));
                }
            }
        }
        return vmax;
    };

    // Zero LDS histograms (used only in passB, after barriers).
    for (int k = tid; k < 2 * NREP * EDGES; k += NTH)
        (&hist[0][0][0])[k] = 0u;

    // ---- Full-row max: other half first, then own half (stays resident for passB).
    stage(half ? 0 : HALF_T);
    __syncthreads();
    float vmax = passA(0.0f);
    __syncthreads();                                 // reads done before overwrite
    stage(half * HALF_T);
    __syncthreads();
    vmax = passA(vmax);

    for (int off = 32; off > 0; off >>= 1)
        vmax = fmaxf(vmax, __shfl_down(vmax, off, 64));
    if ((tid & 63) == 0) sred[tid >> 6] = vmax;
    __syncthreads();
    if (tid == 0) {
        float m = sred[0];
        for (int w = 1; w < NTH / 64; ++w) m = fmaxf(m, sred[w]);
        s_mx = __fsqrt_rn(m);
        wmax[row] = m;    // both siblings store the identical full-row value — benign
    }
    __syncthreads();
    const float mx   = s_mx;                         // RN sqrt of row max sq-distance
    const float invw = 100.0f / mx;                  // guess only — probes are exact

    // Squared-domain thresholds: m_i = smallest float y>=0 with RN(sqrt(y)) >= e[i],
    // e[i] = mx * ((float)i * 0.01f), e[100] = mx (endpoint pinned; mn == 0 exactly
    // from diagonal pairs). Then RN(sqrt(s)) >= e[i] <=> s >= m_i — binning s
    // EXACTLY reproduces the reference (validated absmax 0.0, r6/r10).
    if (tid < EDGES) {
        float e = (tid == EDGES - 1) ? mx : __fmul_rn(mx, __fmul_rn((float)tid, 0.01f));
        float y = 0.0f;                              // e[0] == 0 -> m_0 = 0
        if (tid > 0) {
            y = __fmul_rn(e, e);
            for (int it = 0; it < 4 && __fsqrt_rn(y) < e; ++it)
                y = __int_as_float(__float_as_int(y) + 1);   // safety (shouldn't fire)
            for (int it = 0; it < 8; ++it) {
                float py = __int_as_float(__float_as_int(y) - 1);
                if (__fsqrt_rn(py) >= e) y = py; else break;
            }
        }
        sqe[tid] = y;
    }
    __syncthreads();
    if (tid < NBINS) SQ2[tid] = make_float2(sqe[tid], sqe[tid + 1]);
    __syncthreads();

    // ---- passB over OWN half (resident): k<16 weight 2 (unordered pair),
    // k==16 weight 1 each side ((x-y)^2 == (y-x)^2 bitwise, so exact).
    unsigned int* __restrict__ h1 = &hist[0][a][0];
    unsigned int* __restrict__ h2 = &hist[1][a][0];
    for (int r = 0; r < 2; ++r) {
        const int t = r * 32 + hw;
        if (t < HALF_T) {
            const int b = t * TSTRIDE;
            const float2 o0 = spt[b + a * 3];
            const float2 o1 = spt[b + a * 3 + 1];
            const float2 o2 = spt[b + a * 3 + 2];
#pragma unroll 4
            for (int k = 1; k <= 16; ++k) {
                const int c = b + ((a + k) & 31) * 3;
                const float2 c0 = spt[c], c1 = spt[c + 1], c2 = spt[c + 2];
                float dx1 = o0.x - c0.x, dy1 = o0.y - c0.y, dz1 = o2.x - c2.x;
                float s1 = dx1 * dx1 + dy1 * dy1 + dz1 * dz1;
                float dx2 = o1.x - c1.x, dy2 = o1.y - c1.y, dz2 = o2.y - c2.y;
                float s2 = dx2 * dx2 + dy2 * dy2 + dz2 * dz2;

                int i1 = (int)(sqrt_approx(s1) * invw);      // guess within +-1 (proven)
                int i2 = (int)(sqrt_approx(s2) * invw);
                i1 = i1 < 0 ? 0 : (i1 > 99 ? 99 : i1);
                i2 = i2 < 0 ? 0 : (i2 > 99 ? 99 : i2);
                float2 t1 = SQ2[i1];
                float2 t2 = SQ2[i2];
                i1 += (s1 >= t1.y) ? 1 : 0;                  // exclusive with decrement
                i1 -= (s1 <  t1.x) ? 1 : 0;
                i2 += (s2 >= t2.y) ? 1 : 0;
                i2 -= (s2 <  t2.x) ? 1 : 0;
                i1 = i1 > 99 ? 99 : i1;                      // == reference clip
                i2 = i2 > 99 ? 99 : i2;

                const unsigned int wgt = (k < 16) ? 2u : 1u;
                atomicAdd(&h1[i1], wgt);
                atomicAdd(&h2[i2], wgt);
            }
        }
    }
    __syncthreads();

    // Merge LDS replicas into this block's PRIVATE global slice (plain stores —
    // no zero-init, no atomics, no races; k_jsd sums the two halves).
    if (tid < 2 * NBINS) {
        const int ds = tid / NBINS, bn = tid - ds * NBINS;
        unsigned int s = 0;
        for (int rr = 0; rr < NREP; ++rr) s += hist[ds][rr][bn];
        whist[((row * 2 + half) * 2 + ds) * NBINS + bn] = s;
    }
}

// ---- K2: per-row JSD epilogue (identical arithmetic to the absmax-0.0 version).
__global__ __launch_bounds__(128)
void k_jsd(const float* __restrict__ wmax, const unsigned int* __restrict__ whist,
           float* __restrict__ out)
{
#pragma clang fp contract(off)
    __shared__ float edg[EDGES];
    __shared__ float sterm[NBINS];
    const int tid = threadIdx.x, row = blockIdx.x;
    const float mx = __fsqrt_rn(wmax[row]);
    if (tid < EDGES) {
        float w1 = (tid == EDGES - 1) ? 1.0f : ((float)tid * 0.01f);
        edg[tid] = mx * w1;
    }
    __syncthreads();
    if (tid < NBINS) {
        unsigned int c1 = whist[((row * 2 + 0) * 2 + 0) * NBINS + tid]
                        + whist[((row * 2 + 1) * 2 + 0) * NBINS + tid];
        unsigned int c2 = whist[((row * 2 + 0) * 2 + 1) * NBINS + tid]
                        + whist[((row * 2 + 1) * 2 + 1) * NBINS + tid];
        if (tid == 0) { c1 += T * J; c2 += T * J; }  // diagonal zeros -> bin 0

        float w   = edg[tid + 1] - edg[tid];         // jnp.diff(edges)
        float den = __fmul_rn(NTOT, w);
        float px  = __fdiv_rn((float)c1, den);
        float qx  = __fdiv_rn((float)c2, den);
        float m   = (px + qx) * 0.5f;
        float lm  = logf(m + EPSF);
        sterm[tid] = px * (logf(px + EPSF) - lm) + qx * (logf(qx + EPSF) - lm);
    }
    __syncthreads();
    if (tid == 0) {
        float acc = 0.0f;
        for (int i = 0; i < NBINS; ++i) acc += sterm[i];
        out[row] = acc * 0.5f;
    }
}

extern "C" void kernel_launch(void* const* d_in, const int* in_sizes, int n_in,
                              void* d_out, int out_size, void* d_ws, size_t ws_size,
                              hipStream_t stream) {
    const float* d1 = (const float*)d_in[0];
    const float* d2 = (const float*)d_in[1];
    float* out = (float*)d_out;
    float*        wmax  = (float*)d_ws;
    unsigned int* whist = (unsigned int*)((char*)d_ws + WS_HIST_OFF);

    k_pair<<<BATCH * 2, NTH, 0, stream>>>(d1, d2, wmax, whist);
    k_jsd <<<BATCH, 128, 0, stream>>>(wmax, whist, out);
}